// Round 1
// baseline (949.640 us; speedup 1.0000x reference)
//
#include <hip/hip_runtime.h>
#include <hip/hip_bf16.h>
#include <math.h>

#define DIM_ 1024
#define B_ 4
#define S_ 512
#define H_ 16
#define HD_ 64
// 1/sqrt(64*3)
#define SCORE_SCALE_ 0.07216878364870323f

// ---------------------------------------------------------------------------
// Fused tiled FP32 GEMM: C_z = A @ W_z + b_z for z = 0..gridDim.z-1
// BM=BN=128, BK=16, 256 threads, 8x8 per thread (strided 16 mapping).
// ---------------------------------------------------------------------------
__global__ __launch_bounds__(256) void gemm_bias3(
    const float* __restrict__ A,
    const float* __restrict__ W0, const float* __restrict__ W1, const float* __restrict__ W2,
    const float* __restrict__ b0, const float* __restrict__ b1, const float* __restrict__ b2,
    float* __restrict__ C0, float* __restrict__ C1, float* __restrict__ C2)
{
    const int z = blockIdx.z;
    const float* __restrict__ W    = (z == 0) ? W0 : (z == 1) ? W1 : W2;
    const float* __restrict__ bias = (z == 0) ? b0 : (z == 1) ? b1 : b2;
    float* __restrict__ C          = (z == 0) ? C0 : (z == 1) ? C1 : C2;

    __shared__ float As[16][132];   // [k][m], transposed store
    __shared__ float Bs[16][132];   // [k][n]

    const int t  = threadIdx.x;
    const int m0 = blockIdx.y * 128;
    const int n0 = blockIdx.x * 128;
    const int tx = t & 15;
    const int ty = t >> 4;

    float acc[8][8];
#pragma unroll
    for (int i = 0; i < 8; ++i)
#pragma unroll
        for (int j = 0; j < 8; ++j) acc[i][j] = 0.f;

    const int ar = t >> 2;         // 0..63 (A row within tile, +64 second half)
    const int ac = (t & 3) * 4;    // 0,4,8,12 (A col quad)
    const int br = t >> 5;         // 0..7 (B row, +8 second half)
    const int bc = (t & 31) * 4;   // 0..124 (B col quad)

    for (int kt = 0; kt < 1024; kt += 16) {
        const float4 a0 = *(const float4*)&A[(size_t)(m0 + ar)      * DIM_ + kt + ac];
        const float4 a1 = *(const float4*)&A[(size_t)(m0 + ar + 64) * DIM_ + kt + ac];
        const float4 w0 = *(const float4*)&W[(size_t)(kt + br)     * DIM_ + n0 + bc];
        const float4 w1 = *(const float4*)&W[(size_t)(kt + br + 8) * DIM_ + n0 + bc];

        __syncthreads();   // guard previous iteration's LDS reads

        As[ac + 0][ar] = a0.x; As[ac + 1][ar] = a0.y;
        As[ac + 2][ar] = a0.z; As[ac + 3][ar] = a0.w;
        As[ac + 0][ar + 64] = a1.x; As[ac + 1][ar + 64] = a1.y;
        As[ac + 2][ar + 64] = a1.z; As[ac + 3][ar + 64] = a1.w;
        *(float4*)&Bs[br][bc]     = w0;
        *(float4*)&Bs[br + 8][bc] = w1;

        __syncthreads();

#pragma unroll
        for (int kk = 0; kk < 16; ++kk) {
            float a[8], b[8];
#pragma unroll
            for (int i = 0; i < 8; ++i) a[i] = As[kk][ty + 16 * i];
#pragma unroll
            for (int j = 0; j < 8; ++j) b[j] = Bs[kk][tx + 16 * j];
#pragma unroll
            for (int i = 0; i < 8; ++i)
#pragma unroll
                for (int j = 0; j < 8; ++j)
                    acc[i][j] = fmaf(a[i], b[j], acc[i][j]);
        }
    }

#pragma unroll
    for (int i = 0; i < 8; ++i) {
        const int m = m0 + ty + 16 * i;
#pragma unroll
        for (int j = 0; j < 8; ++j) {
            const int n = n0 + tx + 16 * j;
            C[(size_t)m * DIM_ + n] = acc[i][j] + bias[n];
        }
    }
}

// ---------------------------------------------------------------------------
// Disentangled attention. One block = (b, h, 8 q-rows). 256 threads.
// scores[q,k] = (Q.K + Q.PK[q-k+511] + K.PQ[k-q+511]) * SCORE_SCALE
// ---------------------------------------------------------------------------
#define QT 8
#define KT 32
#define BPAD 69   // row pad: stride 69 -> gcd(69,32)... 69%32=5, conflict-free

__global__ __launch_bounds__(256) void attn_kernel(
    const float* __restrict__ Q, const float* __restrict__ K, const float* __restrict__ V,
    const float* __restrict__ PK, const float* __restrict__ PQ,
    float* __restrict__ out)
{
    const int t  = threadIdx.x;
    const int q0 = blockIdx.x * QT;
    const int b  = blockIdx.y >> 4;
    const int h  = blockIdx.y & 15;

    __shared__ float Qs[QT * BPAD];
    __shared__ float Ss[QT * S_];          // 16 KB scores
    __shared__ float Ks[KT * BPAD];
    __shared__ float PKb[40 * BPAD];       // 39-row band (+1 pad row)
    __shared__ float PQb[40 * BPAD];
    __shared__ float Ps[4][QT][HD_];       // PV partials
    __shared__ float denom[QT];

    const size_t qkv_base = (size_t)b * S_ * DIM_ + (size_t)h * HD_;

    // stage Q tile (8 rows x 64)
    if (t < QT * 16) {
        const int row = t >> 4, cq = (t & 15) * 4;
        const float4 qv = *(const float4*)&Q[qkv_base + (size_t)(q0 + row) * DIM_ + cq];
        Qs[row * BPAD + cq + 0] = qv.x; Qs[row * BPAD + cq + 1] = qv.y;
        Qs[row * BPAD + cq + 2] = qv.z; Qs[row * BPAD + cq + 3] = qv.w;
    }

    const int sq = t >> 5;   // 0..7  local q row
    const int kl = t & 31;   // 0..31 local k col

    for (int k0 = 0; k0 < S_; k0 += KT) {
        __syncthreads();   // guard previous tile's LDS reads (also covers Qs stage)

        // stage K tile: 32 rows x 16 float4
#pragma unroll
        for (int u = 0; u < 2; ++u) {
            const int idx = t + u * 256;
            const int row = idx >> 4, cq = (idx & 15) * 4;
            const float4 kv = *(const float4*)&K[qkv_base + (size_t)(k0 + row) * DIM_ + cq];
            Ks[row * BPAD + cq + 0] = kv.x; Ks[row * BPAD + cq + 1] = kv.y;
            Ks[row * BPAD + cq + 2] = kv.z; Ks[row * BPAD + cq + 3] = kv.w;
        }
        // stage PK band: rows rbase_pk .. rbase_pk+38 ; local r = q - kl + 31
        const int rbase_pk = q0 - k0 + 480;
        for (int idx = t; idx < 39 * 16; idx += 256) {
            const int row = idx >> 4, cq = (idx & 15) * 4;
            int r = rbase_pk + row; r = min(max(r, 0), 2 * S_ - 1);
            const float4 pv = *(const float4*)&PK[(size_t)r * DIM_ + h * HD_ + cq];
            PKb[row * BPAD + cq + 0] = pv.x; PKb[row * BPAD + cq + 1] = pv.y;
            PKb[row * BPAD + cq + 2] = pv.z; PKb[row * BPAD + cq + 3] = pv.w;
        }
        // stage PQ band: local r = kl - q + 7
        const int rbase_pq = k0 - q0 + 504;
        for (int idx = t; idx < 39 * 16; idx += 256) {
            const int row = idx >> 4, cq = (idx & 15) * 4;
            int r = rbase_pq + row; r = min(max(r, 0), 2 * S_ - 1);
            const float4 pv = *(const float4*)&PQ[(size_t)r * DIM_ + h * HD_ + cq];
            PQb[row * BPAD + cq + 0] = pv.x; PQb[row * BPAD + cq + 1] = pv.y;
            PQb[row * BPAD + cq + 2] = pv.z; PQb[row * BPAD + cq + 3] = pv.w;
        }
        __syncthreads();

        // compute 8x32 score elements, one per thread
        float s1 = 0.f, s2 = 0.f, s3 = 0.f;
        const float* __restrict__ qrow  = &Qs[sq * BPAD];
        const float* __restrict__ krow  = &Ks[kl * BPAD];
        const float* __restrict__ pkrow = &PKb[(sq - kl + 31) * BPAD];
        const float* __restrict__ pqrow = &PQb[(kl - sq + 7) * BPAD];
#pragma unroll
        for (int d = 0; d < HD_; ++d) {
            const float qd = qrow[d];
            const float kd = krow[d];
            s1 = fmaf(qd, kd, s1);
            s2 = fmaf(qd, pkrow[d], s2);
            s3 = fmaf(kd, pqrow[d], s3);
        }
        Ss[sq * S_ + k0 + kl] = (s1 + s2 + s3) * SCORE_SCALE_;
    }
    __syncthreads();

    // softmax: 32 threads per q-row (row = sq), shuffle reduce within 32 lanes
    {
        float mx = -1e30f;
        for (int k = kl; k < S_; k += 32) mx = fmaxf(mx, Ss[sq * S_ + k]);
#pragma unroll
        for (int off = 16; off >= 1; off >>= 1) mx = fmaxf(mx, __shfl_xor(mx, off));
        float sum = 0.f;
        for (int k = kl; k < S_; k += 32) {
            const float e = __expf(Ss[sq * S_ + k] - mx);
            Ss[sq * S_ + k] = e;
            sum += e;
        }
#pragma unroll
        for (int off = 16; off >= 1; off >>= 1) sum += __shfl_xor(sum, off);
        if (kl == 0) denom[sq] = sum;
    }
    __syncthreads();

    // PV: thread (g = t/64 owns k-range, d = t%64), acc over 8 q rows
    {
        const int d = t & 63;
        const int g = t >> 6;
        float acc[QT];
#pragma unroll
        for (int q = 0; q < QT; ++q) acc[q] = 0.f;
#pragma unroll 4
        for (int k = g * 128; k < (g + 1) * 128; ++k) {
            const float vkd = V[qkv_base + (size_t)k * DIM_ + d];
#pragma unroll
            for (int q = 0; q < QT; ++q)
                acc[q] = fmaf(Ss[q * S_ + k], vkd, acc[q]);
        }
#pragma unroll
        for (int q = 0; q < QT; ++q) Ps[g][q][d] = acc[q];
    }
    __syncthreads();

    // reduce partials and write out: out[b, q0+q, h*64+d]
    {
        const int d = t & 63;
        const int qb = t >> 6;   // 0..3
#pragma unroll
        for (int u = 0; u < 2; ++u) {
            const int q = qb + u * 4;
            const float r = (Ps[0][q][d] + Ps[1][q][d] + Ps[2][q][d] + Ps[3][q][d]) / denom[q];
            out[((size_t)b * S_ + q0 + q) * DIM_ + (size_t)h * HD_ + d] = r;
        }
    }
}

// ---------------------------------------------------------------------------
extern "C" void kernel_launch(void* const* d_in, const int* in_sizes, int n_in,
                              void* d_out, int out_size, void* d_ws, size_t ws_size,
                              hipStream_t stream) {
    (void)in_sizes; (void)n_in; (void)out_size; (void)ws_size;
    const float* x   = (const float*)d_in[0];
    const float* rel = (const float*)d_in[1];
    const float* Wq  = (const float*)d_in[2];
    const float* bq  = (const float*)d_in[3];
    const float* Wk  = (const float*)d_in[4];
    const float* bk  = (const float*)d_in[5];
    const float* Wv  = (const float*)d_in[6];
    const float* bv  = (const float*)d_in[7];
    float* out = (float*)d_out;

    float* Qb  = (float*)d_ws;                      // 2048 x 1024
    float* Kb  = Qb  + (size_t)2048 * 1024;
    float* Vb  = Kb  + (size_t)2048 * 1024;
    float* PKb = Vb  + (size_t)2048 * 1024;         // 1024 x 1024 (rel @ Wk + bk)
    float* PQb = PKb + (size_t)1024 * 1024;         // 1024 x 1024 (rel @ Wq + bq)

    dim3 blk(256);
    // Q, K, V projections: M = 2048
    gemm_bias3<<<dim3(8, 16, 3), blk, 0, stream>>>(x, Wq, Wk, Wv, bq, bk, bv, Qb, Kb, Vb);
    // pos_k (Wk,bk) and pos_q (Wq,bq): M = 1024
    gemm_bias3<<<dim3(8, 8, 2), blk, 0, stream>>>(rel, Wk, Wq, Wk, bk, bq, bk, PKb, PQb, PKb);
    // attention
    attn_kernel<<<dim3(S_ / QT, B_ * H_), blk, 0, stream>>>(Qb, Kb, Vb, PKb, PQb, out);
}

// Round 2
// 372.347 us; speedup vs baseline: 2.5504x; 2.5504x over previous
//
#include <hip/hip_runtime.h>
#include <math.h>

#define DIM_ 1024
#define B_ 4
#define S_ 512
#define H_ 16
#define HD_ 64
#define SCORE_SCALE_ 0.07216878364870323f

typedef __attribute__((ext_vector_type(8))) short bf16x8;
typedef __attribute__((ext_vector_type(4))) float f32x4;

__device__ __forceinline__ unsigned short f2bf(float f) {
    unsigned int u = __float_as_uint(f);
    u = u + 0x7fffu + ((u >> 16) & 1u);   // RNE (no NaN in data)
    return (unsigned short)(u >> 16);
}
__device__ __forceinline__ float bflo(unsigned int u) { return __uint_as_float(u << 16); }
__device__ __forceinline__ float bfhi(unsigned int u) { return __uint_as_float(u & 0xffff0000u); }
__device__ __forceinline__ float bfs(unsigned short s) { return __uint_as_float(((unsigned int)s) << 16); }

__device__ __forceinline__ void gload16(const void* g, void* l) {
    __builtin_amdgcn_global_load_lds((const __attribute__((address_space(1))) void*)g,
                                     (__attribute__((address_space(3))) void*)l, 16, 0, 0);
}

// ---------------------------------------------------------------------------
// fp32 -> bf16 elementwise (float4 in, ushort4 out)
// ---------------------------------------------------------------------------
__global__ __launch_bounds__(256) void cvt_bf16(const float* __restrict__ src,
                                                unsigned short* __restrict__ dst, int n4) {
    const int i = blockIdx.x * 256 + threadIdx.x;
    if (i >= n4) return;
    const float4 v = *(const float4*)&src[(size_t)i * 4];
    ushort4 o;
    o.x = f2bf(v.x); o.y = f2bf(v.y); o.z = f2bf(v.z); o.w = f2bf(v.w);
    *(ushort4*)&dst[(size_t)i * 4] = o;
}

// ---------------------------------------------------------------------------
// W [k][n] fp32 -> Wt [n][k] bf16 (LDS-tiled 32x32 transpose)
// ---------------------------------------------------------------------------
__global__ __launch_bounds__(256) void wtrans(
    const float* __restrict__ W0, const float* __restrict__ W1, const float* __restrict__ W2,
    unsigned short* __restrict__ T0, unsigned short* __restrict__ T1, unsigned short* __restrict__ T2)
{
    const float* __restrict__ W = blockIdx.z == 0 ? W0 : blockIdx.z == 1 ? W1 : W2;
    unsigned short* __restrict__ T = blockIdx.z == 0 ? T0 : blockIdx.z == 1 ? T1 : T2;
    __shared__ float tile[32][33];
    const int t = threadIdx.x;
    const int n0 = blockIdx.x * 32, k0 = blockIdx.y * 32;
    const int r = t >> 3, c4 = (t & 7) * 4;
    const float4 v = *(const float4*)&W[(size_t)(k0 + r) * DIM_ + n0 + c4];
    tile[r][c4 + 0] = v.x; tile[r][c4 + 1] = v.y; tile[r][c4 + 2] = v.z; tile[r][c4 + 3] = v.w;
    __syncthreads();
    ushort4 o;
    o.x = f2bf(tile[c4 + 0][r]); o.y = f2bf(tile[c4 + 1][r]);
    o.z = f2bf(tile[c4 + 2][r]); o.w = f2bf(tile[c4 + 3][r]);
    *(ushort4*)&T[(size_t)(n0 + r) * DIM_ + k0 + c4] = o;
}

// ---------------------------------------------------------------------------
// bf16 MFMA GEMM (B^T form): C_z[m][n] = sum_k Ab[m][k] * Wt_z[n][k] + bias_z[n]
// BM=BN=128, BK=32, 4 waves (2x2), acc 4x4 of 16x16x32 fragments, dbuf LDS.
// z==2 (Wv) only covers m < 2048.
// ---------------------------------------------------------------------------
__global__ __launch_bounds__(256) void gemm_mfma_bt(
    const unsigned short* __restrict__ Ab,
    const unsigned short* __restrict__ Wt0, const unsigned short* __restrict__ Wt1, const unsigned short* __restrict__ Wt2,
    const float* __restrict__ b0, const float* __restrict__ b1, const float* __restrict__ b2,
    unsigned short* __restrict__ C0, unsigned short* __restrict__ C1, unsigned short* __restrict__ C2)
{
    const int z = blockIdx.z;
    const int m0 = blockIdx.y * 128, n0 = blockIdx.x * 128;
    if (z == 2 && m0 >= 2048) return;
    const unsigned short* __restrict__ Wt = z == 0 ? Wt0 : z == 1 ? Wt1 : Wt2;
    const float* __restrict__ bias        = z == 0 ? b0  : z == 1 ? b1  : b2;
    unsigned short* __restrict__ C        = z == 0 ? C0  : z == 1 ? C1  : C2;

    __shared__ unsigned short As[2][128 * 32];
    __shared__ unsigned short Bs[2][128 * 32];

    const int t = threadIdx.x, lane = t & 63, wave = t >> 6;
    const int wm = wave >> 1, wn = wave & 1;

    f32x4 acc[4][4];
#pragma unroll
    for (int i = 0; i < 4; ++i)
#pragma unroll
        for (int j = 0; j < 4; ++j) acc[i][j] = (f32x4){0.f, 0.f, 0.f, 0.f};

    // staging chunks: 512 x 16B per tile; wave w -> chunks w*64+lane, 256+w*64+lane
    const int c1 = wave * 64 + lane, c2 = c1 + 256;
    const int ar1 = c1 >> 2, ao1 = (c1 & 3) * 8;
    const int ar2 = c2 >> 2, ao2 = (c2 & 3) * 8;
    const int lr = lane & 15, lk = (lane >> 4) * 8;

#define STAGE(buf, kt) { \
    gload16(&Ab[(size_t)(m0 + ar1) * DIM_ + (kt) + ao1], &As[buf][c1 * 8]); \
    gload16(&Ab[(size_t)(m0 + ar2) * DIM_ + (kt) + ao2], &As[buf][c2 * 8]); \
    gload16(&Wt[(size_t)(n0 + ar1) * DIM_ + (kt) + ao1], &Bs[buf][c1 * 8]); \
    gload16(&Wt[(size_t)(n0 + ar2) * DIM_ + (kt) + ao2], &Bs[buf][c2 * 8]); }

    STAGE(0, 0)
    asm volatile("s_waitcnt vmcnt(0)" ::: "memory");
    __syncthreads();

    int cur = 0;
    for (int kt = 0; kt < DIM_; kt += 32) {
        if (kt + 32 < DIM_) STAGE(cur ^ 1, kt + 32)
        bf16x8 af[4], bfr[4];
#pragma unroll
        for (int i = 0; i < 4; ++i) {
            af[i]  = *(const bf16x8*)&As[cur][(wm * 64 + i * 16 + lr) * 32 + lk];
            bfr[i] = *(const bf16x8*)&Bs[cur][(wn * 64 + i * 16 + lr) * 32 + lk];
        }
#pragma unroll
        for (int i = 0; i < 4; ++i)
#pragma unroll
            for (int j = 0; j < 4; ++j)
                acc[i][j] = __builtin_amdgcn_mfma_f32_16x16x32_bf16(af[i], bfr[j], acc[i][j], 0, 0, 0);
        asm volatile("s_waitcnt vmcnt(0)" ::: "memory");
        __syncthreads();
        cur ^= 1;
    }
#undef STAGE

    const int rb = (lane >> 4) * 4;
#pragma unroll
    for (int j = 0; j < 4; ++j) {
        const int col = n0 + wn * 64 + j * 16 + lr;
        const float bv = bias[col];
#pragma unroll
        for (int i = 0; i < 4; ++i) {
            const int row = m0 + wm * 64 + i * 16 + rb;
#pragma unroll
            for (int r = 0; r < 4; ++r)
                C[(size_t)(row + r) * DIM_ + col] = f2bf(acc[i][j][r] + bv);
        }
    }
}

// ---------------------------------------------------------------------------
// Disentangled attention, bf16 inputs. One block = (b, h, 8 q-rows), 256 thr.
// LDS tiles bf16 (stride 72), ds_read_b128 (8 bf16/read) + inline convert.
// ---------------------------------------------------------------------------
#define QT 8
#define KT 32
#define RST 72

__global__ __launch_bounds__(256) void attn_kernel(
    const unsigned short* __restrict__ Q, const unsigned short* __restrict__ K,
    const unsigned short* __restrict__ V,
    const unsigned short* __restrict__ PK, const unsigned short* __restrict__ PQ,
    float* __restrict__ out)
{
    const int t = threadIdx.x;
    const int q0 = blockIdx.x * QT;
    const int b = blockIdx.y >> 4, h = blockIdx.y & 15;

    __shared__ unsigned short Qs[QT * RST];
    __shared__ unsigned short Ks[KT * RST];
    __shared__ unsigned short PKs[40 * RST];
    __shared__ unsigned short PQs[40 * RST];
    __shared__ float Ss[QT * S_];
    __shared__ float Ps[4][QT][HD_];
    __shared__ float denom[QT];

    const size_t base = (size_t)b * S_ * DIM_ + (size_t)h * HD_;

    // stage Q tile: 8 rows x 8 chunks of 8 bf16
    if (t < QT * 8) {
        const int row = t >> 3, c8 = (t & 7) * 8;
        const uint4 v = *(const uint4*)&Q[base + (size_t)(q0 + row) * DIM_ + c8];
        *(uint4*)&Qs[row * RST + c8] = v;
    }

    const int sq = t >> 5;   // 0..7
    const int kl = t & 31;   // 0..31

    for (int k0 = 0; k0 < S_; k0 += KT) {
        __syncthreads();   // guard previous tile reads (also covers Qs stage)

        {   // K tile: 32 rows x 8 chunks = 256 = blockDim
            const int row = t >> 3, c8 = (t & 7) * 8;
            const uint4 v = *(const uint4*)&K[base + (size_t)(k0 + row) * DIM_ + c8];
            *(uint4*)&Ks[row * RST + c8] = v;
        }
        const int rbase_pk = q0 - k0 + 480;   // global PK row = rbase + local; local = sq-kl+31
        for (int idx = t; idx < 39 * 8; idx += 256) {
            const int row = idx >> 3, c8 = (idx & 7) * 8;
            int r = rbase_pk + row; r = min(max(r, 0), 2 * S_ - 1);
            const uint4 v = *(const uint4*)&PK[(size_t)r * DIM_ + h * HD_ + c8];
            *(uint4*)&PKs[row * RST + c8] = v;
        }
        const int rbase_pq = k0 - q0 + 504;   // local = kl-sq+7
        for (int idx = t; idx < 39 * 8; idx += 256) {
            const int row = idx >> 3, c8 = (idx & 7) * 8;
            int r = rbase_pq + row; r = min(max(r, 0), 2 * S_ - 1);
            const uint4 v = *(const uint4*)&PQ[(size_t)r * DIM_ + h * HD_ + c8];
            *(uint4*)&PQs[row * RST + c8] = v;
        }
        __syncthreads();

        float s1 = 0.f, s2 = 0.f, s3 = 0.f;
        const unsigned short* __restrict__ qrow  = &Qs[sq * RST];
        const unsigned short* __restrict__ krow  = &Ks[kl * RST];
        const unsigned short* __restrict__ pkrow = &PKs[(sq - kl + 31) * RST];
        const unsigned short* __restrict__ pqrow = &PQs[(kl - sq + 7) * RST];
#pragma unroll
        for (int c = 0; c < 64; c += 8) {
            const uint4 qu  = *(const uint4*)&qrow[c];
            const uint4 ku  = *(const uint4*)&krow[c];
            const uint4 pku = *(const uint4*)&pkrow[c];
            const uint4 pqu = *(const uint4*)&pqrow[c];
#define DOT2(qc, kc, pc, rc) { \
            const float a0 = bflo(qc), a1 = bfhi(qc); \
            const float b0_ = bflo(kc), b1_ = bfhi(kc); \
            s1 = fmaf(a0, b0_, s1); s1 = fmaf(a1, b1_, s1); \
            s2 = fmaf(a0, bflo(pc), s2); s2 = fmaf(a1, bfhi(pc), s2); \
            s3 = fmaf(b0_, bflo(rc), s3); s3 = fmaf(b1_, bfhi(rc), s3); }
            DOT2(qu.x, ku.x, pku.x, pqu.x)
            DOT2(qu.y, ku.y, pku.y, pqu.y)
            DOT2(qu.z, ku.z, pku.z, pqu.z)
            DOT2(qu.w, ku.w, pku.w, pqu.w)
#undef DOT2
        }
        Ss[sq * S_ + k0 + kl] = (s1 + s2 + s3) * SCORE_SCALE_;
    }
    __syncthreads();

    // softmax: 32 threads per q-row, shuffle reduce
    {
        float mx = -1e30f;
        for (int k = kl; k < S_; k += 32) mx = fmaxf(mx, Ss[sq * S_ + k]);
#pragma unroll
        for (int off = 16; off >= 1; off >>= 1) mx = fmaxf(mx, __shfl_xor(mx, off));
        float sum = 0.f;
        for (int k = kl; k < S_; k += 32) {
            const float e = __expf(Ss[sq * S_ + k] - mx);
            Ss[sq * S_ + k] = e;
            sum += e;
        }
#pragma unroll
        for (int off = 16; off >= 1; off >>= 1) sum += __shfl_xor(sum, off);
        if (kl == 0) denom[sq] = sum;
    }
    __syncthreads();

    // PV: thread (g = t/64 owns 128 k, d = t%64)
    {
        const int d = t & 63;
        const int g = t >> 6;
        float acc[QT];
#pragma unroll
        for (int q = 0; q < QT; ++q) acc[q] = 0.f;
#pragma unroll 4
        for (int k = g * 128; k < (g + 1) * 128; ++k) {
            const float vkd = bfs(V[base + (size_t)k * DIM_ + d]);
#pragma unroll
            for (int q = 0; q < QT; ++q)
                acc[q] = fmaf(Ss[q * S_ + k], vkd, acc[q]);
        }
#pragma unroll
        for (int q = 0; q < QT; ++q) Ps[g][q][d] = acc[q];
    }
    __syncthreads();

    {
        const int d = t & 63;
        const int qb = t >> 6;
#pragma unroll
        for (int u = 0; u < 2; ++u) {
            const int q = qb + u * 4;
            const float r = (Ps[0][q][d] + Ps[1][q][d] + Ps[2][q][d] + Ps[3][q][d]) / denom[q];
            out[((size_t)b * S_ + q0 + q) * DIM_ + (size_t)h * HD_ + d] = r;
        }
    }
}

// ---------------------------------------------------------------------------
extern "C" void kernel_launch(void* const* d_in, const int* in_sizes, int n_in,
                              void* d_out, int out_size, void* d_ws, size_t ws_size,
                              hipStream_t stream) {
    (void)in_sizes; (void)n_in; (void)out_size; (void)ws_size;
    const float* x   = (const float*)d_in[0];
    const float* rel = (const float*)d_in[1];
    const float* Wq  = (const float*)d_in[2];
    const float* bq  = (const float*)d_in[3];
    const float* Wk  = (const float*)d_in[4];
    const float* bk  = (const float*)d_in[5];
    const float* Wv  = (const float*)d_in[6];
    const float* bv  = (const float*)d_in[7];
    float* out = (float*)d_out;

    // workspace (bf16): Ab = [x; rel] (3072x1024), Wt q/k/v (1024x1024 each),
    // Cq = Q|PQ (3072x1024), Ck = K|PK (3072x1024), Cv = V (2048x1024)  -> 28 MB
    unsigned short* Ab  = (unsigned short*)d_ws;
    unsigned short* Wtq = Ab  + (size_t)3072 * 1024;
    unsigned short* Wtk = Wtq + (size_t)1024 * 1024;
    unsigned short* Wtv = Wtk + (size_t)1024 * 1024;
    unsigned short* Cq  = Wtv + (size_t)1024 * 1024;
    unsigned short* Ck  = Cq  + (size_t)3072 * 1024;
    unsigned short* Cv  = Ck  + (size_t)3072 * 1024;

    cvt_bf16<<<2048, 256, 0, stream>>>(x,   Ab,                       524288);
    cvt_bf16<<<1024, 256, 0, stream>>>(rel, Ab + (size_t)2048 * 1024, 262144);
    wtrans<<<dim3(32, 32, 3), 256, 0, stream>>>(Wq, Wk, Wv, Wtq, Wtk, Wtv);
    gemm_mfma_bt<<<dim3(8, 24, 3), 256, 0, stream>>>(Ab, Wtq, Wtk, Wtv, bq, bk, bv, Cq, Ck, Cv);
    attn_kernel<<<dim3(S_ / QT, B_ * H_), 256, 0, stream>>>(
        Cq, Ck, Cv, Ck + (size_t)2048 * 1024, Cq + (size_t)2048 * 1024, out);
}

// Round 3
// 159.170 us; speedup vs baseline: 5.9662x; 2.3393x over previous
//
#include <hip/hip_runtime.h>
#include <math.h>

#define DIM_ 1024
#define B_ 4
#define S_ 512
#define H_ 16
#define HD_ 64
#define SCORE_SCALE_ 0.07216878364870323f

typedef __attribute__((ext_vector_type(8))) short bf16x8;
typedef __attribute__((ext_vector_type(4))) float f32x4;

__device__ __forceinline__ unsigned short f2bf(float f) {
    unsigned int u = __float_as_uint(f);
    u = u + 0x7fffu + ((u >> 16) & 1u);   // RNE (no NaN in data)
    return (unsigned short)(u >> 16);
}
__device__ __forceinline__ float bflo(unsigned int u) { return __uint_as_float(u << 16); }
__device__ __forceinline__ float bfhi(unsigned int u) { return __uint_as_float(u & 0xffff0000u); }
__device__ __forceinline__ float bfs(unsigned short s) { return __uint_as_float(((unsigned int)s) << 16); }

__device__ __forceinline__ void gload16(const void* g, void* l) {
    __builtin_amdgcn_global_load_lds((const __attribute__((address_space(1))) void*)g,
                                     (__attribute__((address_space(3))) void*)l, 16, 0, 0);
}

// ---------------------------------------------------------------------------
// fp32 -> bf16 elementwise
// ---------------------------------------------------------------------------
__global__ __launch_bounds__(256) void cvt_bf16(const float* __restrict__ src,
                                                unsigned short* __restrict__ dst, int n4) {
    const int i = blockIdx.x * 256 + threadIdx.x;
    if (i >= n4) return;
    const float4 v = *(const float4*)&src[(size_t)i * 4];
    ushort4 o;
    o.x = f2bf(v.x); o.y = f2bf(v.y); o.z = f2bf(v.z); o.w = f2bf(v.w);
    *(ushort4*)&dst[(size_t)i * 4] = o;
}

// ---------------------------------------------------------------------------
// W [k][n] fp32 -> Wt [n][k] bf16
// ---------------------------------------------------------------------------
__global__ __launch_bounds__(256) void wtrans(
    const float* __restrict__ W0, const float* __restrict__ W1, const float* __restrict__ W2,
    unsigned short* __restrict__ T0, unsigned short* __restrict__ T1, unsigned short* __restrict__ T2)
{
    const float* __restrict__ W = blockIdx.z == 0 ? W0 : blockIdx.z == 1 ? W1 : W2;
    unsigned short* __restrict__ T = blockIdx.z == 0 ? T0 : blockIdx.z == 1 ? T1 : T2;
    __shared__ float tile[32][33];
    const int t = threadIdx.x;
    const int n0 = blockIdx.x * 32, k0 = blockIdx.y * 32;
    const int r = t >> 3, c4 = (t & 7) * 4;
    const float4 v = *(const float4*)&W[(size_t)(k0 + r) * DIM_ + n0 + c4];
    tile[r][c4 + 0] = v.x; tile[r][c4 + 1] = v.y; tile[r][c4 + 2] = v.z; tile[r][c4 + 3] = v.w;
    __syncthreads();
    ushort4 o;
    o.x = f2bf(tile[c4 + 0][r]); o.y = f2bf(tile[c4 + 1][r]);
    o.z = f2bf(tile[c4 + 2][r]); o.w = f2bf(tile[c4 + 3][r]);
    *(ushort4*)&T[(size_t)(n0 + r) * DIM_ + k0 + c4] = o;
}

// ---------------------------------------------------------------------------
// bf16 MFMA GEMM (B^T form), as in round 2.
// ---------------------------------------------------------------------------
__global__ __launch_bounds__(256) void gemm_mfma_bt(
    const unsigned short* __restrict__ Ab,
    const unsigned short* __restrict__ Wt0, const unsigned short* __restrict__ Wt1, const unsigned short* __restrict__ Wt2,
    const float* __restrict__ b0, const float* __restrict__ b1, const float* __restrict__ b2,
    unsigned short* __restrict__ C0, unsigned short* __restrict__ C1, unsigned short* __restrict__ C2)
{
    const int z = blockIdx.z;
    const int m0 = blockIdx.y * 128, n0 = blockIdx.x * 128;
    if (z == 2 && m0 >= 2048) return;
    const unsigned short* __restrict__ Wt = z == 0 ? Wt0 : z == 1 ? Wt1 : Wt2;
    const float* __restrict__ bias        = z == 0 ? b0  : z == 1 ? b1  : b2;
    unsigned short* __restrict__ C        = z == 0 ? C0  : z == 1 ? C1  : C2;

    __shared__ unsigned short As[2][128 * 32];
    __shared__ unsigned short Bs[2][128 * 32];

    const int t = threadIdx.x, lane = t & 63, wave = t >> 6;
    const int wm = wave >> 1, wn = wave & 1;

    f32x4 acc[4][4];
#pragma unroll
    for (int i = 0; i < 4; ++i)
#pragma unroll
        for (int j = 0; j < 4; ++j) acc[i][j] = (f32x4){0.f, 0.f, 0.f, 0.f};

    const int c1 = wave * 64 + lane, c2 = c1 + 256;
    const int ar1 = c1 >> 2, ao1 = (c1 & 3) * 8;
    const int ar2 = c2 >> 2, ao2 = (c2 & 3) * 8;
    const int lr = lane & 15, lk = (lane >> 4) * 8;

#define STAGE(buf, kt) { \
    gload16(&Ab[(size_t)(m0 + ar1) * DIM_ + (kt) + ao1], &As[buf][c1 * 8]); \
    gload16(&Ab[(size_t)(m0 + ar2) * DIM_ + (kt) + ao2], &As[buf][c2 * 8]); \
    gload16(&Wt[(size_t)(n0 + ar1) * DIM_ + (kt) + ao1], &Bs[buf][c1 * 8]); \
    gload16(&Wt[(size_t)(n0 + ar2) * DIM_ + (kt) + ao2], &Bs[buf][c2 * 8]); }

    STAGE(0, 0)
    asm volatile("s_waitcnt vmcnt(0)" ::: "memory");
    __syncthreads();

    int cur = 0;
    for (int kt = 0; kt < DIM_; kt += 32) {
        if (kt + 32 < DIM_) STAGE(cur ^ 1, kt + 32)
        bf16x8 af[4], bfr[4];
#pragma unroll
        for (int i = 0; i < 4; ++i) {
            af[i]  = *(const bf16x8*)&As[cur][(wm * 64 + i * 16 + lr) * 32 + lk];
            bfr[i] = *(const bf16x8*)&Bs[cur][(wn * 64 + i * 16 + lr) * 32 + lk];
        }
#pragma unroll
        for (int i = 0; i < 4; ++i)
#pragma unroll
            for (int j = 0; j < 4; ++j)
                acc[i][j] = __builtin_amdgcn_mfma_f32_16x16x32_bf16(af[i], bfr[j], acc[i][j], 0, 0, 0);
        asm volatile("s_waitcnt vmcnt(0)" ::: "memory");
        __syncthreads();
        cur ^= 1;
    }
#undef STAGE

    const int rb = (lane >> 4) * 4;
#pragma unroll
    for (int j = 0; j < 4; ++j) {
        const int col = n0 + wn * 64 + j * 16 + lr;
        const float bv = bias[col];
#pragma unroll
        for (int i = 0; i < 4; ++i) {
            const int row = m0 + wm * 64 + i * 16 + rb;
#pragma unroll
            for (int r = 0; r < 4; ++r)
                C[(size_t)(row + r) * DIM_ + col] = f2bf(acc[i][j][r] + bv);
        }
    }
}

// ---------------------------------------------------------------------------
// bias_c2p: bias[q,k] = Q[q] . PK[q-k+511]   (write, no read)
// block = (qtile 64, b*16+h). G = Q_tile @ PKband^T in 5 chunks of 128 cols.
// ---------------------------------------------------------------------------
__global__ __launch_bounds__(256) void bias_c2p(
    const unsigned short* __restrict__ Q, const unsigned short* __restrict__ PK,
    float* __restrict__ bias)
{
    const int t = threadIdx.x, lane = t & 63, wave = t >> 6;
    const int lr = lane & 15, lg = lane >> 4;
    const int q0 = blockIdx.x * 64;
    const int b = blockIdx.y >> 4, h = blockIdx.y & 15;
    const size_t base = (size_t)b * S_ * DIM_ + h * HD_;
    const size_t bias_base = (size_t)blockIdx.y * S_ * S_;

    __shared__ unsigned short PKb[128 * 72];

    bf16x8 af_q[2];
    {
        const int qrow = q0 + wave * 16 + lr;
#pragma unroll
        for (int ks = 0; ks < 2; ++ks)
            af_q[ks] = *(const bf16x8*)&Q[base + (size_t)qrow * DIM_ + ks * 32 + lg * 8];
    }

    const int strow = t >> 1, stc = (t & 1) * 32;

    for (int c = 0; c < 5; ++c) {
        __syncthreads();
        {
            int gr = q0 + c * 128 + strow; gr = min(gr, 2 * S_ - 1);
            const unsigned short* src = &PK[(size_t)gr * DIM_ + h * HD_ + stc];
            uint4 v0 = ((const uint4*)src)[0], v1 = ((const uint4*)src)[1];
            uint4 v2 = ((const uint4*)src)[2], v3 = ((const uint4*)src)[3];
            uint4* dst = (uint4*)&PKb[strow * 72 + stc];
            dst[0] = v0; dst[1] = v1; dst[2] = v2; dst[3] = v3;
        }
        __syncthreads();

        f32x4 G[8];
#pragma unroll
        for (int rf = 0; rf < 8; ++rf) G[rf] = (f32x4){0.f, 0.f, 0.f, 0.f};
#pragma unroll
        for (int ks = 0; ks < 2; ++ks)
#pragma unroll
            for (int rf = 0; rf < 8; ++rf) {
                const bf16x8 bp = *(const bf16x8*)&PKb[(rf * 16 + lr) * 72 + ks * 32 + lg * 8];
                G[rf] = __builtin_amdgcn_mfma_f32_16x16x32_bf16(af_q[ks], bp, G[rf], 0, 0, 0);
            }
#pragma unroll
        for (int rf = 0; rf < 8; ++rf)
#pragma unroll
            for (int reg = 0; reg < 4; ++reg) {
                const int u = lg * 4 + reg;
                const int k = wave * 16 + u + 511 - c * 128 - (rf * 16 + lr);
                if (k >= 0 && k < S_)
                    bias[bias_base + (size_t)(q0 + wave * 16 + u) * S_ + k] = G[rf][reg];
            }
    }
}

// ---------------------------------------------------------------------------
// bias_p2c: bias[q,k] += K[k] . PQ[k-q+511]
// block = (ktile 64, b*16+h). H = K_tile @ PQband^T, LDS transpose, coalesced RMW.
// ---------------------------------------------------------------------------
__global__ __launch_bounds__(256) void bias_p2c(
    const unsigned short* __restrict__ K, const unsigned short* __restrict__ PQ,
    float* __restrict__ bias)
{
    const int t = threadIdx.x, lane = t & 63, wave = t >> 6;
    const int lr = lane & 15, lg = lane >> 4;
    const int k0 = blockIdx.x * 64;
    const int b = blockIdx.y >> 4, h = blockIdx.y & 15;
    const size_t base = (size_t)b * S_ * DIM_ + h * HD_;
    const size_t bias_base = (size_t)blockIdx.y * S_ * S_;

    __shared__ unsigned short PQb[128 * 72];
    __shared__ float H_lds[64 * 130];

    bf16x8 af_k[2];
    {
        const int krow = k0 + wave * 16 + lr;
#pragma unroll
        for (int ks = 0; ks < 2; ++ks)
            af_k[ks] = *(const bf16x8*)&K[base + (size_t)krow * DIM_ + ks * 32 + lg * 8];
    }

    const int strow = t >> 1, stc = (t & 1) * 32;
    const int w = t & 63, qoff = t >> 6;

    for (int c = 0; c < 5; ++c) {
        __syncthreads();
        {
            int gr = k0 + c * 128 + strow; gr = min(gr, 2 * S_ - 1);
            const unsigned short* src = &PQ[(size_t)gr * DIM_ + h * HD_ + stc];
            uint4 v0 = ((const uint4*)src)[0], v1 = ((const uint4*)src)[1];
            uint4 v2 = ((const uint4*)src)[2], v3 = ((const uint4*)src)[3];
            uint4* dst = (uint4*)&PQb[strow * 72 + stc];
            dst[0] = v0; dst[1] = v1; dst[2] = v2; dst[3] = v3;
        }
        __syncthreads();

        f32x4 Hh[8];
#pragma unroll
        for (int rf = 0; rf < 8; ++rf) Hh[rf] = (f32x4){0.f, 0.f, 0.f, 0.f};
#pragma unroll
        for (int ks = 0; ks < 2; ++ks)
#pragma unroll
            for (int rf = 0; rf < 8; ++rf) {
                const bf16x8 bp = *(const bf16x8*)&PQb[(rf * 16 + lr) * 72 + ks * 32 + lg * 8];
                Hh[rf] = __builtin_amdgcn_mfma_f32_16x16x32_bf16(af_k[ks], bp, Hh[rf], 0, 0, 0);
            }
#pragma unroll
        for (int rf = 0; rf < 8; ++rf)
#pragma unroll
            for (int reg = 0; reg < 4; ++reg)
                H_lds[(wave * 16 + lg * 4 + reg) * 130 + rf * 16 + lr] = Hh[rf][reg];
        __syncthreads();

        const int D = 511 - c * 128;
        const int qlo = max(0, D - 127), qhi = min(S_, D + 64);
        for (int q = qlo + qoff; q < qhi; q += 4) {
            const int rl = w + D - q;
            if (rl >= 0 && rl < 128)
                bias[bias_base + (size_t)q * S_ + k0 + w] += H_lds[w * 130 + rl];
        }
    }
}

// ---------------------------------------------------------------------------
// flash_attn: per (b,h,q-tile 64): online-softmax flash with additive bias.
// 4 waves, wave owns 16 q rows. All matmuls MFMA 16x16x32 bf16.
// ---------------------------------------------------------------------------
__global__ __launch_bounds__(256) void flash_attn(
    const unsigned short* __restrict__ Q, const unsigned short* __restrict__ K,
    const unsigned short* __restrict__ V, const float* __restrict__ bias,
    float* __restrict__ out)
{
    const int t = threadIdx.x, lane = t & 63, wave = t >> 6;
    const int lr = lane & 15, lg = lane >> 4;
    const int q0 = blockIdx.x * 64;
    const int b = blockIdx.y >> 4, h = blockIdx.y & 15;
    const size_t base = (size_t)b * S_ * DIM_ + h * HD_;
    const size_t bias_base = (size_t)blockIdx.y * S_ * S_;

    __shared__ unsigned short K_lds[64 * 72];
    __shared__ unsigned short Vt_lds[64 * 72];   // [d][k]
    __shared__ unsigned short P_lds[64 * 72];

    bf16x8 af_q[2];
    {
        const int qrow = q0 + wave * 16 + lr;
#pragma unroll
        for (int ks = 0; ks < 2; ++ks)
            af_q[ks] = *(const bf16x8*)&Q[base + (size_t)qrow * DIM_ + ks * 32 + lg * 8];
    }

    f32x4 O_acc[4];
#pragma unroll
    for (int df = 0; df < 4; ++df) O_acc[df] = (f32x4){0.f, 0.f, 0.f, 0.f};
    float m_run[4], l_run[4];
#pragma unroll
    for (int r = 0; r < 4; ++r) { m_run[r] = -1e30f; l_run[r] = 0.f; }

    const int st_row = t >> 2, st_c = (t & 3) * 16;

    for (int k0 = 0; k0 < S_; k0 += 64) {
        // prefetch bias tile into regs (issues early, hides under staging)
        float bb[16];
#pragma unroll
        for (int sf = 0; sf < 4; ++sf)
#pragma unroll
            for (int reg = 0; reg < 4; ++reg)
                bb[sf * 4 + reg] = bias[bias_base +
                    (size_t)(q0 + wave * 16 + lg * 4 + reg) * S_ + k0 + sf * 16 + lr];

        __syncthreads();   // guard previous iteration's LDS reads
        {
            const unsigned short* ksrc = &K[base + (size_t)(k0 + st_row) * DIM_ + st_c];
            const uint4 kv0 = ((const uint4*)ksrc)[0], kv1 = ((const uint4*)ksrc)[1];
            uint4* kdst = (uint4*)&K_lds[st_row * 72 + st_c];
            kdst[0] = kv0; kdst[1] = kv1;
            const unsigned short* vsrc = &V[base + (size_t)(k0 + st_row) * DIM_ + st_c];
            const uint4 vv0 = ((const uint4*)vsrc)[0], vv1 = ((const uint4*)vsrc)[1];
            const unsigned short* pv0 = (const unsigned short*)&vv0;
            const unsigned short* pv1 = (const unsigned short*)&vv1;
#pragma unroll
            for (int j = 0; j < 8; ++j) {
                Vt_lds[(st_c + j) * 72 + st_row]     = pv0[j];
                Vt_lds[(st_c + 8 + j) * 72 + st_row] = pv1[j];
            }
        }
        __syncthreads();

        // S = Q @ K^T
        f32x4 S_acc[4];
#pragma unroll
        for (int sf = 0; sf < 4; ++sf) S_acc[sf] = (f32x4){0.f, 0.f, 0.f, 0.f};
#pragma unroll
        for (int ks = 0; ks < 2; ++ks)
#pragma unroll
            for (int sf = 0; sf < 4; ++sf) {
                const bf16x8 bk = *(const bf16x8*)&K_lds[(sf * 16 + lr) * 72 + ks * 32 + lg * 8];
                S_acc[sf] = __builtin_amdgcn_mfma_f32_16x16x32_bf16(af_q[ks], bk, S_acc[sf], 0, 0, 0);
            }

        // scores + online softmax
        float sv[16];
#pragma unroll
        for (int sf = 0; sf < 4; ++sf)
#pragma unroll
            for (int reg = 0; reg < 4; ++reg)
                sv[sf * 4 + reg] = (S_acc[sf][reg] + bb[sf * 4 + reg]) * SCORE_SCALE_;

        float mt[4];
#pragma unroll
        for (int reg = 0; reg < 4; ++reg)
            mt[reg] = fmaxf(fmaxf(sv[reg], sv[4 + reg]), fmaxf(sv[8 + reg], sv[12 + reg]));
#pragma unroll
        for (int off = 8; off >= 1; off >>= 1)
#pragma unroll
            for (int reg = 0; reg < 4; ++reg)
                mt[reg] = fmaxf(mt[reg], __shfl_xor(mt[reg], off));

        float al[4], rs[4];
#pragma unroll
        for (int reg = 0; reg < 4; ++reg) {
            const float mn = fmaxf(m_run[reg], mt[reg]);
            al[reg] = __expf(m_run[reg] - mn);
            m_run[reg] = mn;
            rs[reg] = 0.f;
        }
        unsigned short pb[16];
#pragma unroll
        for (int sf = 0; sf < 4; ++sf)
#pragma unroll
            for (int reg = 0; reg < 4; ++reg) {
                const float p = __expf(sv[sf * 4 + reg] - m_run[reg]);
                const unsigned short pr = f2bf(p);
                pb[sf * 4 + reg] = pr;
                rs[reg] += bfs(pr);   // denominator consistent with bf16 P
            }
#pragma unroll
        for (int off = 8; off >= 1; off >>= 1)
#pragma unroll
            for (int reg = 0; reg < 4; ++reg)
                rs[reg] += __shfl_xor(rs[reg], off);
#pragma unroll
        for (int reg = 0; reg < 4; ++reg)
            l_run[reg] = l_run[reg] * al[reg] + rs[reg];
#pragma unroll
        for (int df = 0; df < 4; ++df)
#pragma unroll
            for (int reg = 0; reg < 4; ++reg)
                O_acc[df][reg] *= al[reg];

        // write P (own wave's rows only; same-wave RAW handled by lgkmcnt)
#pragma unroll
        for (int sf = 0; sf < 4; ++sf)
#pragma unroll
            for (int reg = 0; reg < 4; ++reg)
                P_lds[(wave * 16 + lg * 4 + reg) * 72 + sf * 16 + lr] = pb[sf * 4 + reg];

        // O += P @ V
#pragma unroll
        for (int ks = 0; ks < 2; ++ks) {
            const bf16x8 ap = *(const bf16x8*)&P_lds[(wave * 16 + lr) * 72 + ks * 32 + lg * 8];
#pragma unroll
            for (int df = 0; df < 4; ++df) {
                const bf16x8 bv = *(const bf16x8*)&Vt_lds[(df * 16 + lr) * 72 + ks * 32 + lg * 8];
                O_acc[df] = __builtin_amdgcn_mfma_f32_16x16x32_bf16(ap, bv, O_acc[df], 0, 0, 0);
            }
        }
    }

#pragma unroll
    for (int df = 0; df < 4; ++df)
#pragma unroll
        for (int reg = 0; reg < 4; ++reg)
            out[((size_t)b * S_ + q0 + wave * 16 + lg * 4 + reg) * DIM_ +
                h * HD_ + df * 16 + lr] = O_acc[df][reg] / l_run[reg];
}

// ---------------------------------------------------------------------------
// Fallback attention (round-2), used when ws_size is too small for bias buf.
// ---------------------------------------------------------------------------
#define QT 8
#define KT 32
#define RST 72

__global__ __launch_bounds__(256) void attn_kernel(
    const unsigned short* __restrict__ Q, const unsigned short* __restrict__ K,
    const unsigned short* __restrict__ V,
    const unsigned short* __restrict__ PK, const unsigned short* __restrict__ PQ,
    float* __restrict__ out)
{
    const int t = threadIdx.x;
    const int q0 = blockIdx.x * QT;
    const int b = blockIdx.y >> 4, h = blockIdx.y & 15;

    __shared__ unsigned short Qs[QT * RST];
    __shared__ unsigned short Ks[KT * RST];
    __shared__ unsigned short PKs[40 * RST];
    __shared__ unsigned short PQs[40 * RST];
    __shared__ float Ss[QT * S_];
    __shared__ float Ps[4][QT][HD_];
    __shared__ float denom[QT];

    const size_t base = (size_t)b * S_ * DIM_ + (size_t)h * HD_;

    if (t < QT * 8) {
        const int row = t >> 3, c8 = (t & 7) * 8;
        const uint4 v = *(const uint4*)&Q[base + (size_t)(q0 + row) * DIM_ + c8];
        *(uint4*)&Qs[row * RST + c8] = v;
    }

    const int sq = t >> 5;
    const int kl = t & 31;

    for (int k0 = 0; k0 < S_; k0 += KT) {
        __syncthreads();
        {
            const int row = t >> 3, c8 = (t & 7) * 8;
            const uint4 v = *(const uint4*)&K[base + (size_t)(k0 + row) * DIM_ + c8];
            *(uint4*)&Ks[row * RST + c8] = v;
        }
        const int rbase_pk = q0 - k0 + 480;
        for (int idx = t; idx < 39 * 8; idx += 256) {
            const int row = idx >> 3, c8 = (idx & 7) * 8;
            int r = rbase_pk + row; r = min(max(r, 0), 2 * S_ - 1);
            const uint4 v = *(const uint4*)&PK[(size_t)r * DIM_ + h * HD_ + c8];
            *(uint4*)&PKs[row * RST + c8] = v;
        }
        const int rbase_pq = k0 - q0 + 504;
        for (int idx = t; idx < 39 * 8; idx += 256) {
            const int row = idx >> 3, c8 = (idx & 7) * 8;
            int r = rbase_pq + row; r = min(max(r, 0), 2 * S_ - 1);
            const uint4 v = *(const uint4*)&PQ[(size_t)r * DIM_ + h * HD_ + c8];
            *(uint4*)&PQs[row * RST + c8] = v;
        }
        __syncthreads();

        float s1 = 0.f, s2 = 0.f, s3 = 0.f;
        const unsigned short* __restrict__ qrow  = &Qs[sq * RST];
        const unsigned short* __restrict__ krow  = &Ks[kl * RST];
        const unsigned short* __restrict__ pkrow = &PKs[(sq - kl + 31) * RST];
        const unsigned short* __restrict__ pqrow = &PQs[(kl - sq + 7) * RST];
#pragma unroll
        for (int c = 0; c < 64; c += 8) {
            const uint4 qu  = *(const uint4*)&qrow[c];
            const uint4 ku  = *(const uint4*)&krow[c];
            const uint4 pku = *(const uint4*)&pkrow[c];
            const uint4 pqu = *(const uint4*)&pqrow[c];
#define DOT2(qc, kc, pc, rc) { \
            const float a0 = bflo(qc), a1 = bfhi(qc); \
            const float b0_ = bflo(kc), b1_ = bfhi(kc); \
            s1 = fmaf(a0, b0_, s1); s1 = fmaf(a1, b1_, s1); \
            s2 = fmaf(a0, bflo(pc), s2); s2 = fmaf(a1, bfhi(pc), s2); \
            s3 = fmaf(b0_, bflo(rc), s3); s3 = fmaf(b1_, bfhi(rc), s3); }
            DOT2(qu.x, ku.x, pku.x, pqu.x)
            DOT2(qu.y, ku.y, pku.y, pqu.y)
            DOT2(qu.z, ku.z, pku.z, pqu.z)
            DOT2(qu.w, ku.w, pku.w, pqu.w)
#undef DOT2
        }
        Ss[sq * S_ + k0 + kl] = (s1 + s2 + s3) * SCORE_SCALE_;
    }
    __syncthreads();

    {
        float mx = -1e30f;
        for (int k = kl; k < S_; k += 32) mx = fmaxf(mx, Ss[sq * S_ + k]);
#pragma unroll
        for (int off = 16; off >= 1; off >>= 1) mx = fmaxf(mx, __shfl_xor(mx, off));
        float sum = 0.f;
        for (int k = kl; k < S_; k += 32) {
            const float e = __expf(Ss[sq * S_ + k] - mx);
            Ss[sq * S_ + k] = e;
            sum += e;
        }
#pragma unroll
        for (int off = 16; off >= 1; off >>= 1) sum += __shfl_xor(sum, off);
        if (kl == 0) denom[sq] = sum;
    }
    __syncthreads();

    {
        const int d = t & 63;
        const int g = t >> 6;
        float acc[QT];
#pragma unroll
        for (int q = 0; q < QT; ++q) acc[q] = 0.f;
#pragma unroll 4
        for (int k = g * 128; k < (g + 1) * 128; ++k) {
            const float vkd = bfs(V[base + (size_t)k * DIM_ + d]);
#pragma unroll
            for (int q = 0; q < QT; ++q)
                acc[q] = fmaf(Ss[q * S_ + k], vkd, acc[q]);
        }
#pragma unroll
        for (int q = 0; q < QT; ++q) Ps[g][q][d] = acc[q];
    }
    __syncthreads();

    {
        const int d = t & 63;
        const int qb = t >> 6;
#pragma unroll
        for (int u = 0; u < 2; ++u) {
            const int q = qb + u * 4;
            const float r = (Ps[0][q][d] + Ps[1][q][d] + Ps[2][q][d] + Ps[3][q][d]) / denom[q];
            out[((size_t)b * S_ + q0 + q) * DIM_ + (size_t)h * HD_ + d] = r;
        }
    }
}

// ---------------------------------------------------------------------------
extern "C" void kernel_launch(void* const* d_in, const int* in_sizes, int n_in,
                              void* d_out, int out_size, void* d_ws, size_t ws_size,
                              hipStream_t stream) {
    (void)in_sizes; (void)n_in; (void)out_size;
    const float* x   = (const float*)d_in[0];
    const float* rel = (const float*)d_in[1];
    const float* Wq  = (const float*)d_in[2];
    const float* bq  = (const float*)d_in[3];
    const float* Wk  = (const float*)d_in[4];
    const float* bk  = (const float*)d_in[5];
    const float* Wv  = (const float*)d_in[6];
    const float* bv  = (const float*)d_in[7];
    float* out = (float*)d_out;

    unsigned short* Ab  = (unsigned short*)d_ws;      // [x(2048); rel(1024)] x 1024
    unsigned short* Wtq = Ab  + (size_t)3072 * 1024;
    unsigned short* Wtk = Wtq + (size_t)1024 * 1024;
    unsigned short* Wtv = Wtk + (size_t)1024 * 1024;
    unsigned short* Cq  = Wtv + (size_t)1024 * 1024;  // Q(2048 rows) | PQ(1024 rows)
    unsigned short* Ck  = Cq  + (size_t)3072 * 1024;  // K | PK
    unsigned short* Cv  = Ck  + (size_t)3072 * 1024;  // V (2048 rows)
    float* bias = (float*)(Cv + (size_t)2048 * 1024); // B*H*S*S f32 = 67.1 MB

    const size_t ws_needed = (size_t)14680064 * 2 + (size_t)B_ * H_ * S_ * S_ * 4;

    cvt_bf16<<<2048, 256, 0, stream>>>(x,   Ab,                       524288);
    cvt_bf16<<<1024, 256, 0, stream>>>(rel, Ab + (size_t)2048 * 1024, 262144);
    wtrans<<<dim3(32, 32, 3), 256, 0, stream>>>(Wq, Wk, Wv, Wtq, Wtk, Wtv);
    gemm_mfma_bt<<<dim3(8, 24, 3), 256, 0, stream>>>(Ab, Wtq, Wtk, Wtv, bq, bk, bv, Cq, Ck, Cv);

    const unsigned short* PKp = Ck + (size_t)2048 * 1024;
    const unsigned short* PQp = Cq + (size_t)2048 * 1024;

    if (ws_size >= ws_needed) {
        bias_c2p<<<dim3(8, 64), 256, 0, stream>>>(Cq, PKp, bias);
        bias_p2c<<<dim3(8, 64), 256, 0, stream>>>(Ck, PQp, bias);
        flash_attn<<<dim3(8, 64), 256, 0, stream>>>(Cq, Ck, Cv, bias, out);
    } else {
        attn_kernel<<<dim3(S_ / QT, B_ * H_), 256, 0, stream>>>(Cq, Ck, Cv, PKp, PQp, out);
    }
}

// Round 4
// 97.857 us; speedup vs baseline: 9.7044x; 1.6266x over previous
//
#include <hip/hip_runtime.h>
#include <math.h>

#define DIM_ 1024
#define B_ 4
#define S_ 512
#define H_ 16
#define HD_ 64
#define SCORE_SCALE_ 0.07216878364870323f

typedef __attribute__((ext_vector_type(8))) short bf16x8;
typedef __attribute__((ext_vector_type(4))) float f32x4;

__device__ __forceinline__ unsigned short f2bf(float f) {
    unsigned int u = __float_as_uint(f);
    u = u + 0x7fffu + ((u >> 16) & 1u);   // RNE (no NaN in data)
    return (unsigned short)(u >> 16);
}
__device__ __forceinline__ float bfs(unsigned short s) { return __uint_as_float(((unsigned int)s) << 16); }

__device__ __forceinline__ void gload16(const void* g, void* l) {
    __builtin_amdgcn_global_load_lds((const __attribute__((address_space(1))) void*)g,
                                     (__attribute__((address_space(3))) void*)l, 16, 0, 0);
}

// ---------------------------------------------------------------------------
// fp32 -> bf16 elementwise
// ---------------------------------------------------------------------------
__global__ __launch_bounds__(256) void cvt_bf16(const float* __restrict__ src,
                                                unsigned short* __restrict__ dst, int n4) {
    const int i = blockIdx.x * 256 + threadIdx.x;
    if (i >= n4) return;
    const float4 v = *(const float4*)&src[(size_t)i * 4];
    ushort4 o;
    o.x = f2bf(v.x); o.y = f2bf(v.y); o.z = f2bf(v.z); o.w = f2bf(v.w);
    *(ushort4*)&dst[(size_t)i * 4] = o;
}

// ---------------------------------------------------------------------------
// W [k][n] fp32 -> Wt [n][k] bf16
// ---------------------------------------------------------------------------
__global__ __launch_bounds__(256) void wtrans(
    const float* __restrict__ W0, const float* __restrict__ W1, const float* __restrict__ W2,
    unsigned short* __restrict__ T0, unsigned short* __restrict__ T1, unsigned short* __restrict__ T2)
{
    const float* __restrict__ W = blockIdx.z == 0 ? W0 : blockIdx.z == 1 ? W1 : W2;
    unsigned short* __restrict__ T = blockIdx.z == 0 ? T0 : blockIdx.z == 1 ? T1 : T2;
    __shared__ float tile[32][33];
    const int t = threadIdx.x;
    const int n0 = blockIdx.x * 32, k0 = blockIdx.y * 32;
    const int r = t >> 3, c4 = (t & 7) * 4;
    const float4 v = *(const float4*)&W[(size_t)(k0 + r) * DIM_ + n0 + c4];
    tile[r][c4 + 0] = v.x; tile[r][c4 + 1] = v.y; tile[r][c4 + 2] = v.z; tile[r][c4 + 3] = v.w;
    __syncthreads();
    ushort4 o;
    o.x = f2bf(tile[c4 + 0][r]); o.y = f2bf(tile[c4 + 1][r]);
    o.z = f2bf(tile[c4 + 2][r]); o.w = f2bf(tile[c4 + 3][r]);
    *(ushort4*)&T[(size_t)(n0 + r) * DIM_ + k0 + c4] = o;
}

// ---------------------------------------------------------------------------
// bf16 MFMA GEMM (B^T form), as in rounds 2/3.
// ---------------------------------------------------------------------------
__global__ __launch_bounds__(256) void gemm_mfma_bt(
    const unsigned short* __restrict__ Ab,
    const unsigned short* __restrict__ Wt0, const unsigned short* __restrict__ Wt1, const unsigned short* __restrict__ Wt2,
    const float* __restrict__ b0, const float* __restrict__ b1, const float* __restrict__ b2,
    unsigned short* __restrict__ C0, unsigned short* __restrict__ C1, unsigned short* __restrict__ C2)
{
    const int z = blockIdx.z;
    const int m0 = blockIdx.y * 128, n0 = blockIdx.x * 128;
    if (z == 2 && m0 >= 2048) return;
    const unsigned short* __restrict__ Wt = z == 0 ? Wt0 : z == 1 ? Wt1 : Wt2;
    const float* __restrict__ bias        = z == 0 ? b0  : z == 1 ? b1  : b2;
    unsigned short* __restrict__ C        = z == 0 ? C0  : z == 1 ? C1  : C2;

    __shared__ unsigned short As[2][128 * 32];
    __shared__ unsigned short Bs[2][128 * 32];

    const int t = threadIdx.x, lane = t & 63, wave = t >> 6;
    const int wm = wave >> 1, wn = wave & 1;

    f32x4 acc[4][4];
#pragma unroll
    for (int i = 0; i < 4; ++i)
#pragma unroll
        for (int j = 0; j < 4; ++j) acc[i][j] = (f32x4){0.f, 0.f, 0.f, 0.f};

    const int c1 = wave * 64 + lane, c2 = c1 + 256;
    const int ar1 = c1 >> 2, ao1 = (c1 & 3) * 8;
    const int ar2 = c2 >> 2, ao2 = (c2 & 3) * 8;
    const int lr = lane & 15, lk = (lane >> 4) * 8;

#define STAGE(buf, kt) { \
    gload16(&Ab[(size_t)(m0 + ar1) * DIM_ + (kt) + ao1], &As[buf][c1 * 8]); \
    gload16(&Ab[(size_t)(m0 + ar2) * DIM_ + (kt) + ao2], &As[buf][c2 * 8]); \
    gload16(&Wt[(size_t)(n0 + ar1) * DIM_ + (kt) + ao1], &Bs[buf][c1 * 8]); \
    gload16(&Wt[(size_t)(n0 + ar2) * DIM_ + (kt) + ao2], &Bs[buf][c2 * 8]); }

    STAGE(0, 0)
    asm volatile("s_waitcnt vmcnt(0)" ::: "memory");
    __syncthreads();

    int cur = 0;
    for (int kt = 0; kt < DIM_; kt += 32) {
        if (kt + 32 < DIM_) STAGE(cur ^ 1, kt + 32)
        bf16x8 af[4], bfr[4];
#pragma unroll
        for (int i = 0; i < 4; ++i) {
            af[i]  = *(const bf16x8*)&As[cur][(wm * 64 + i * 16 + lr) * 32 + lk];
            bfr[i] = *(const bf16x8*)&Bs[cur][(wn * 64 + i * 16 + lr) * 32 + lk];
        }
#pragma unroll
        for (int i = 0; i < 4; ++i)
#pragma unroll
            for (int j = 0; j < 4; ++j)
                acc[i][j] = __builtin_amdgcn_mfma_f32_16x16x32_bf16(af[i], bfr[j], acc[i][j], 0, 0, 0);
        asm volatile("s_waitcnt vmcnt(0)" ::: "memory");
        __syncthreads();
        cur ^= 1;
    }
#undef STAGE

    const int rb = (lane >> 4) * 4;
#pragma unroll
    for (int j = 0; j < 4; ++j) {
        const int col = n0 + wn * 64 + j * 16 + lr;
        const float bv = bias[col];
#pragma unroll
        for (int i = 0; i < 4; ++i) {
            const int row = m0 + wm * 64 + i * 16 + rb;
#pragma unroll
            for (int r = 0; r < 4; ++r)
                C[(size_t)(row + r) * DIM_ + col] = f2bf(acc[i][j][r] + bv);
        }
    }
}

// ---------------------------------------------------------------------------
// fused_attn: per (b,h,q-tile 64): flash attention with on-the-fly banded
// relative-position bias. Per k-tile:
//   S   = Q_tile @ K_tile^T                         (MFMA)
//   G   = Q_tile @ PK[q0-k0+448 .. +575]^T          (MFMA, 64x128)
//   H   = K_tile @ PQ[k0-q0+448 .. +575]^T          (MFMA, 64x128)
//   Sb[lq][lk] = G[lq][lq+63-lk] + H[lk][lk+63-lq]  (LDS diagonal scatter)
//   scores = (S + Sb) * SCALE -> online softmax -> O += P @ V
// Note: clip(q-k+511,0,1023) never binds at S=512, so bands are exact.
// ---------------------------------------------------------------------------
__global__ __launch_bounds__(256) void fused_attn(
    const unsigned short* __restrict__ Q, const unsigned short* __restrict__ K,
    const unsigned short* __restrict__ V,
    const unsigned short* __restrict__ PK, const unsigned short* __restrict__ PQ,
    float* __restrict__ out)
{
    const int t = threadIdx.x, lane = t & 63, wave = t >> 6;
    const int lr = lane & 15, lg = lane >> 4;
    const int q0 = blockIdx.x * 64;
    const int b = blockIdx.y >> 4, h = blockIdx.y & 15;
    const size_t base = (size_t)b * S_ * DIM_ + h * HD_;

    __shared__ unsigned short KP_lds[64 * 72];   // K tile; reused for P after H
    __shared__ unsigned short Vt_lds[64 * 72];   // V transposed [d][k]
    __shared__ unsigned short PKb[128 * 72];
    __shared__ unsigned short PQb[128 * 72];
    __shared__ float Sb[64 * 65];                // bias tile

    bf16x8 af_q[2];
    {
        const int qrow = q0 + wave * 16 + lr;
#pragma unroll
        for (int ks = 0; ks < 2; ++ks)
            af_q[ks] = *(const bf16x8*)&Q[base + (size_t)qrow * DIM_ + ks * 32 + lg * 8];
    }

    f32x4 O_acc[4];
#pragma unroll
    for (int df = 0; df < 4; ++df) O_acc[df] = (f32x4){0.f, 0.f, 0.f, 0.f};
    float m_run[4], l_run[4];
#pragma unroll
    for (int r = 0; r < 4; ++r) { m_run[r] = -1e30f; l_run[r] = 0.f; }

    const int strow = t >> 3;        // 0..31
    const int stc   = (t & 7) * 8;   // 0..56

    for (int k0 = 0; k0 < S_; k0 += 64) {
        const int rbG = q0 - k0 + 448;   // PK band base (always in [0,1023])
        const int rbH = k0 - q0 + 448;   // PQ band base

        __syncthreads();   // protect LDS vs previous iteration's readers

        // stage K (rows) + V (transposed)
#pragma unroll
        for (int p = 0; p < 2; ++p) {
            const int row = p * 32 + strow;
            const uint4 kv = *(const uint4*)&K[base + (size_t)(k0 + row) * DIM_ + stc];
            *(uint4*)&KP_lds[row * 72 + stc] = kv;
            const uint4 vv = *(const uint4*)&V[base + (size_t)(k0 + row) * DIM_ + stc];
            const unsigned short* pv = (const unsigned short*)&vv;
#pragma unroll
            for (int j = 0; j < 8; ++j)
                Vt_lds[(stc + j) * 72 + row] = pv[j];
        }
        // stage PK / PQ bands (128 rows x 64)
#pragma unroll
        for (int p = 0; p < 4; ++p) {
            const int row = p * 32 + strow;
            *(uint4*)&PKb[row * 72 + stc] =
                *(const uint4*)&PK[(size_t)(rbG + row) * DIM_ + h * HD_ + stc];
            *(uint4*)&PQb[row * 72 + stc] =
                *(const uint4*)&PQ[(size_t)(rbH + row) * DIM_ + h * HD_ + stc];
        }
        __syncthreads();

        // S = Q @ K^T
        f32x4 S_acc[4];
#pragma unroll
        for (int sf = 0; sf < 4; ++sf) S_acc[sf] = (f32x4){0.f, 0.f, 0.f, 0.f};
#pragma unroll
        for (int ks = 0; ks < 2; ++ks)
#pragma unroll
            for (int sf = 0; sf < 4; ++sf) {
                const bf16x8 bk = *(const bf16x8*)&KP_lds[(sf * 16 + lr) * 72 + ks * 32 + lg * 8];
                S_acc[sf] = __builtin_amdgcn_mfma_f32_16x16x32_bf16(af_q[ks], bk, S_acc[sf], 0, 0, 0);
            }

        const int lqr = wave * 16 + lg * 4;   // this thread's 4 rows: lqr+reg

        // G = Q @ PKband^T ; scatter diagonal into Sb (init)
        {
            f32x4 G[8];
#pragma unroll
            for (int rf = 0; rf < 8; ++rf) G[rf] = (f32x4){0.f, 0.f, 0.f, 0.f};
#pragma unroll
            for (int ks = 0; ks < 2; ++ks)
#pragma unroll
                for (int rf = 0; rf < 8; ++rf) {
                    const bf16x8 bp = *(const bf16x8*)&PKb[(rf * 16 + lr) * 72 + ks * 32 + lg * 8];
                    G[rf] = __builtin_amdgcn_mfma_f32_16x16x32_bf16(af_q[ks], bp, G[rf], 0, 0, 0);
                }
#pragma unroll
            for (int rf = 0; rf < 8; ++rf)
#pragma unroll
                for (int reg = 0; reg < 4; ++reg) {
                    const int lq = lqr + reg;
                    const int lk = lq + 63 - (rf * 16 + lr);
                    if ((unsigned)lk < 64u) Sb[lq * 65 + lk] = G[rf][reg];
                }
        }
        __syncthreads();   // all G writes done before H accumulate

        // H = K @ PQband^T ; scatter-accumulate transposed diagonal
        {
            bf16x8 af_k[2];
#pragma unroll
            for (int ks = 0; ks < 2; ++ks)
                af_k[ks] = *(const bf16x8*)&KP_lds[(wave * 16 + lr) * 72 + ks * 32 + lg * 8];
            f32x4 Hf[8];
#pragma unroll
            for (int rf = 0; rf < 8; ++rf) Hf[rf] = (f32x4){0.f, 0.f, 0.f, 0.f};
#pragma unroll
            for (int ks = 0; ks < 2; ++ks)
#pragma unroll
                for (int rf = 0; rf < 8; ++rf) {
                    const bf16x8 bp = *(const bf16x8*)&PQb[(rf * 16 + lr) * 72 + ks * 32 + lg * 8];
                    Hf[rf] = __builtin_amdgcn_mfma_f32_16x16x32_bf16(af_k[ks], bp, Hf[rf], 0, 0, 0);
                }
#pragma unroll
            for (int rf = 0; rf < 8; ++rf)
#pragma unroll
                for (int reg = 0; reg < 4; ++reg) {
                    const int lk = lqr + reg;          // wave's k rows
                    const int lq = lk + 63 - (rf * 16 + lr);
                    if ((unsigned)lq < 64u) Sb[lq * 65 + lk] += Hf[rf][reg];
                }
        }
        __syncthreads();   // Sb final; K_lds free for P reuse

        // scores + online softmax
        float sv[16];
#pragma unroll
        for (int sf = 0; sf < 4; ++sf)
#pragma unroll
            for (int reg = 0; reg < 4; ++reg)
                sv[sf * 4 + reg] =
                    (S_acc[sf][reg] + Sb[(lqr + reg) * 65 + sf * 16 + lr]) * SCORE_SCALE_;

        float mt[4];
#pragma unroll
        for (int reg = 0; reg < 4; ++reg)
            mt[reg] = fmaxf(fmaxf(sv[reg], sv[4 + reg]), fmaxf(sv[8 + reg], sv[12 + reg]));
#pragma unroll
        for (int off = 8; off >= 1; off >>= 1)
#pragma unroll
            for (int reg = 0; reg < 4; ++reg)
                mt[reg] = fmaxf(mt[reg], __shfl_xor(mt[reg], off));

        float al[4], rs[4];
#pragma unroll
        for (int reg = 0; reg < 4; ++reg) {
            const float mn = fmaxf(m_run[reg], mt[reg]);
            al[reg] = __expf(m_run[reg] - mn);
            m_run[reg] = mn;
            rs[reg] = 0.f;
        }
        unsigned short pb[16];
#pragma unroll
        for (int sf = 0; sf < 4; ++sf)
#pragma unroll
            for (int reg = 0; reg < 4; ++reg) {
                const float p = __expf(sv[sf * 4 + reg] - m_run[reg]);
                const unsigned short pr = f2bf(p);
                pb[sf * 4 + reg] = pr;
                rs[reg] += bfs(pr);
            }
#pragma unroll
        for (int off = 8; off >= 1; off >>= 1)
#pragma unroll
            for (int reg = 0; reg < 4; ++reg)
                rs[reg] += __shfl_xor(rs[reg], off);
#pragma unroll
        for (int reg = 0; reg < 4; ++reg)
            l_run[reg] = l_run[reg] * al[reg] + rs[reg];
#pragma unroll
        for (int df = 0; df < 4; ++df)
#pragma unroll
            for (int reg = 0; reg < 4; ++reg)
                O_acc[df][reg] *= al[reg];

        // P into KP_lds (own wave's rows; same-wave RAW via lgkmcnt ordering)
#pragma unroll
        for (int sf = 0; sf < 4; ++sf)
#pragma unroll
            for (int reg = 0; reg < 4; ++reg)
                KP_lds[(lqr + reg) * 72 + sf * 16 + lr] = pb[sf * 4 + reg];

        // O += P @ V
#pragma unroll
        for (int ks = 0; ks < 2; ++ks) {
            const bf16x8 ap = *(const bf16x8*)&KP_lds[(wave * 16 + lr) * 72 + ks * 32 + lg * 8];
#pragma unroll
            for (int df = 0; df < 4; ++df) {
                const bf16x8 bv = *(const bf16x8*)&Vt_lds[(df * 16 + lr) * 72 + ks * 32 + lg * 8];
                O_acc[df] = __builtin_amdgcn_mfma_f32_16x16x32_bf16(ap, bv, O_acc[df], 0, 0, 0);
            }
        }
    }

#pragma unroll
    for (int df = 0; df < 4; ++df)
#pragma unroll
        for (int reg = 0; reg < 4; ++reg)
            out[((size_t)b * S_ + q0 + wave * 16 + lg * 4 + reg) * DIM_ +
                h * HD_ + df * 16 + lr] = O_acc[df][reg] / l_run[reg];
}

// ---------------------------------------------------------------------------
extern "C" void kernel_launch(void* const* d_in, const int* in_sizes, int n_in,
                              void* d_out, int out_size, void* d_ws, size_t ws_size,
                              hipStream_t stream) {
    (void)in_sizes; (void)n_in; (void)out_size; (void)ws_size;
    const float* x   = (const float*)d_in[0];
    const float* rel = (const float*)d_in[1];
    const float* Wq  = (const float*)d_in[2];
    const float* bq  = (const float*)d_in[3];
    const float* Wk  = (const float*)d_in[4];
    const float* bk  = (const float*)d_in[5];
    const float* Wv  = (const float*)d_in[6];
    const float* bv  = (const float*)d_in[7];
    float* out = (float*)d_out;

    unsigned short* Ab  = (unsigned short*)d_ws;      // [x(2048); rel(1024)] x 1024
    unsigned short* Wtq = Ab  + (size_t)3072 * 1024;
    unsigned short* Wtk = Wtq + (size_t)1024 * 1024;
    unsigned short* Wtv = Wtk + (size_t)1024 * 1024;
    unsigned short* Cq  = Wtv + (size_t)1024 * 1024;  // Q(2048 rows) | PQ(1024 rows)
    unsigned short* Ck  = Cq  + (size_t)3072 * 1024;  // K | PK
    unsigned short* Cv  = Ck  + (size_t)3072 * 1024;  // V (2048 rows)

    cvt_bf16<<<2048, 256, 0, stream>>>(x,   Ab,                       524288);
    cvt_bf16<<<1024, 256, 0, stream>>>(rel, Ab + (size_t)2048 * 1024, 262144);
    wtrans<<<dim3(32, 32, 3), 256, 0, stream>>>(Wq, Wk, Wv, Wtq, Wtk, Wtv);
    gemm_mfma_bt<<<dim3(8, 24, 3), 256, 0, stream>>>(Ab, Wtq, Wtk, Wtv, bq, bk, bv, Cq, Ck, Cv);

    const unsigned short* PKp = Ck + (size_t)2048 * 1024;   // rel @ Wk
    const unsigned short* PQp = Cq + (size_t)2048 * 1024;   // rel @ Wq

    fused_attn<<<dim3(8, 64), 256, 0, stream>>>(Cq, Ck, Cv, PKp, PQp, out);
}